// Round 1
// baseline (2549.006 us; speedup 1.0000x reference)
//
#include <hip/hip_runtime.h>
#include <hip/hip_bf16.h>

#define CC 192
#define NH 6
#define HD 32
#define SW 64      // tokens per window
#define NBLK 4096  // B * Hb * Wb

// workspace layout (floats)
#define WS_WQ 0
#define WS_WK 36864
#define WS_WV 73728
#define WS_WO 110592
#define WS_BQ 147456   // then BK, BV, BO each +192

__device__ __forceinline__ float blo(unsigned u){ return __uint_as_float(u << 16); }
__device__ __forceinline__ float bhi(unsigned u){ return __uint_as_float(u & 0xffff0000u); }
__device__ __forceinline__ unsigned short f2b(float f){
  unsigned u = __float_as_uint(f);
  return (unsigned short)((u + 0x7fffu + ((u >> 16) & 1u)) >> 16);
}

// Fold conv1x1 + MHA in-projection (and out-projection + conv1x1) into single
// 192x192 matrices, stored TRANSPOSED: WT[ci][o] for coalesced reads.
__global__ void fuse_weights(const float* __restrict__ wq, const float* __restrict__ bq,
                             const float* __restrict__ wk, const float* __restrict__ bk,
                             const float* __restrict__ wv, const float* __restrict__ bv,
                             const float* __restrict__ in_w, const float* __restrict__ in_b,
                             const float* __restrict__ out_w, const float* __restrict__ out_b,
                             const float* __restrict__ proj_w, const float* __restrict__ proj_b,
                             float* __restrict__ ws)
{
  int mat = blockIdx.x / CC;
  int ci  = blockIdx.x % CC;
  int o   = threadIdx.x;
  const float *A, *Bm, *bsmall, *badd; int aoff, boff;
  if (mat == 0)      { A=in_w;   aoff=0;     Bm=wq;    bsmall=bq;    badd=in_b;   boff=0;   }
  else if (mat == 1) { A=in_w;   aoff=CC;    Bm=wk;    bsmall=bk;    badd=in_b;   boff=CC;  }
  else if (mat == 2) { A=in_w;   aoff=2*CC;  Bm=wv;    bsmall=bv;    badd=in_b;   boff=2*CC;}
  else               { A=proj_w; aoff=0;     Bm=out_w; bsmall=out_b; badd=proj_b; boff=0;   }
  const float* arow = A + (size_t)(aoff + o) * CC;
  float acc = 0.f;
  for (int m = 0; m < CC; ++m) acc = fmaf(arow[m], Bm[m*CC + ci], acc);
  ws[mat*36864 + ci*CC + o] = acc;
  if (ci == 0){
    float bacc = 0.f;
    for (int m = 0; m < CC; ++m) bacc = fmaf(arow[m], bsmall[m], bacc);
    ws[WS_BQ + mat*CC + o] = bacc + badd[boff + o];
  }
}

__global__ __launch_bounds__(256, 1) void win_attn(
    const float* __restrict__ q2d, const float* __restrict__ kv2d,
    const float* __restrict__ ws, float* __restrict__ out)
{
  __shared__ float Xs[CC*68];              // X[c][tok], stride 68
  __shared__ unsigned short qe[SW*200];    // qe[tok][c] bf16, stride 200
  __shared__ unsigned short ke[SW*200];
  __shared__ unsigned short ve[SW*200];
  __shared__ unsigned short oT[CC*72];     // oT[c][tok] bf16, stride 72

  const int t = threadIdx.x;
  const int widx = blockIdx.x;
  const int b  = widx >> 10;
  const int l  = widx & 1023;
  const int y0 = (l >> 5) << 3;
  const int x0 = (l & 31) << 3;

  const size_t imgbase = (size_t)b * CC * 256 * 256;
  const float* qb  = q2d  + imgbase;
  const float* kvb = kv2d + imgbase;

  const int tg = t & 15, og = t >> 4;      // 16 tok-groups x 16 o-groups
  const int tok0 = tg * 4, o0 = og * 12;

  // ---------- helpers ----------
  auto loadX = [&](const float* __restrict__ src){
    #pragma unroll
    for (int i = 0; i < 12; ++i){
      int lin = i*256 + t;                 // (c, tok/4), 3072 float4s
      int c = lin >> 4, tq = lin & 15;
      int tok = tq << 2;
      int dy = tok >> 3, dx = tok & 7;     // dx in {0,4}
      float4 v = *(const float4*)&src[(c*256 + y0 + dy)*256 + x0 + dx];
      *(float4*)&Xs[c*68 + tok] = v;
    }
  };

  auto proj = [&](const float* __restrict__ WT, const float* __restrict__ bias,
                  unsigned short* __restrict__ dst){
    float acc[4][12];
    #pragma unroll
    for (int j = 0; j < 12; ++j){
      float bj = bias[o0 + j];
      acc[0][j]=bj; acc[1][j]=bj; acc[2][j]=bj; acc[3][j]=bj;
    }
    #pragma unroll 4
    for (int c = 0; c < CC; ++c){
      float4 xv = *(const float4*)&Xs[c*68 + tok0];
      float4 w0 = *(const float4*)&WT[c*CC + o0];
      float4 w1 = *(const float4*)&WT[c*CC + o0 + 4];
      float4 w2 = *(const float4*)&WT[c*CC + o0 + 8];
      float xx[4] = {xv.x, xv.y, xv.z, xv.w};
      float ww[12] = {w0.x,w0.y,w0.z,w0.w,w1.x,w1.y,w1.z,w1.w,w2.x,w2.y,w2.z,w2.w};
      #pragma unroll
      for (int ii = 0; ii < 4; ++ii)
        #pragma unroll
        for (int j = 0; j < 12; ++j)
          acc[ii][j] = fmaf(xx[ii], ww[j], acc[ii][j]);
    }
    #pragma unroll
    for (int ii = 0; ii < 4; ++ii){
      unsigned* d32 = (unsigned*)(dst + (tok0+ii)*200 + o0);  // o0 even -> aligned
      #pragma unroll
      for (int j6 = 0; j6 < 6; ++j6){
        unsigned lo = f2b(acc[ii][2*j6]);
        unsigned hi = f2b(acc[ii][2*j6+1]);
        d32[j6] = lo | (hi << 16);
      }
    }
  };

  // ---------- pipeline ----------
  loadX(qb);
  __syncthreads();
  proj(ws + WS_WQ, ws + WS_BQ, qe);
  __syncthreads();                 // all Xs reads done before overwrite
  loadX(kvb);
  __syncthreads();
  proj(ws + WS_WK, ws + WS_BQ + CC, ke);
  proj(ws + WS_WV, ws + WS_BQ + 2*CC, ve);
  __syncthreads();

  // ---------- attention: one (head, row) per task ----------
  #pragma unroll
  for (int it = 0; it < 2; ++it){
    int task = it*256 + t;
    if (task < NH*SW){
      int h = task >> 6, s = task & 63;
      float q[32];
      {
        const uint4* r = (const uint4*)(qe + s*200 + h*32);
        #pragma unroll
        for (int g = 0; g < 4; ++g){
          uint4 a = r[g];
          q[g*8+0]=blo(a.x); q[g*8+1]=bhi(a.x);
          q[g*8+2]=blo(a.y); q[g*8+3]=bhi(a.y);
          q[g*8+4]=blo(a.z); q[g*8+5]=bhi(a.z);
          q[g*8+6]=blo(a.w); q[g*8+7]=bhi(a.w);
        }
      }
      float p[64];
      #pragma unroll 2
      for (int t2 = 0; t2 < 64; ++t2){
        const uint4* r = (const uint4*)(ke + t2*200 + h*32);
        float dot = 0.f;
        #pragma unroll
        for (int g = 0; g < 4; ++g){
          uint4 a = r[g];
          dot = fmaf(q[g*8+0], blo(a.x), dot);
          dot = fmaf(q[g*8+1], bhi(a.x), dot);
          dot = fmaf(q[g*8+2], blo(a.y), dot);
          dot = fmaf(q[g*8+3], bhi(a.y), dot);
          dot = fmaf(q[g*8+4], blo(a.z), dot);
          dot = fmaf(q[g*8+5], bhi(a.z), dot);
          dot = fmaf(q[g*8+6], blo(a.w), dot);
          dot = fmaf(q[g*8+7], bhi(a.w), dot);
        }
        p[t2] = dot * 0.17677669529663687f;   // 1/sqrt(32)
      }
      float m = p[0];
      #pragma unroll
      for (int i2 = 1; i2 < 64; ++i2) m = fmaxf(m, p[i2]);
      float sum = 0.f;
      #pragma unroll
      for (int i2 = 0; i2 < 64; ++i2){ p[i2] = __expf(p[i2] - m); sum += p[i2]; }
      float inv = 1.f / sum;
      #pragma unroll
      for (int i2 = 0; i2 < 64; ++i2) p[i2] *= inv;
      float oacc[32];
      #pragma unroll
      for (int d = 0; d < 32; ++d) oacc[d] = 0.f;
      #pragma unroll 2
      for (int t2 = 0; t2 < 64; ++t2){
        const uint4* r = (const uint4*)(ve + t2*200 + h*32);
        float pv = p[t2];
        #pragma unroll
        for (int g = 0; g < 4; ++g){
          uint4 a = r[g];
          oacc[g*8+0] = fmaf(pv, blo(a.x), oacc[g*8+0]);
          oacc[g*8+1] = fmaf(pv, bhi(a.x), oacc[g*8+1]);
          oacc[g*8+2] = fmaf(pv, blo(a.y), oacc[g*8+2]);
          oacc[g*8+3] = fmaf(pv, bhi(a.y), oacc[g*8+3]);
          oacc[g*8+4] = fmaf(pv, blo(a.z), oacc[g*8+4]);
          oacc[g*8+5] = fmaf(pv, bhi(a.z), oacc[g*8+5]);
          oacc[g*8+6] = fmaf(pv, blo(a.w), oacc[g*8+6]);
          oacc[g*8+7] = fmaf(pv, bhi(a.w), oacc[g*8+7]);
        }
      }
      #pragma unroll
      for (int d = 0; d < 32; ++d) oT[(h*32+d)*72 + s] = f2b(oacc[d]);
    }
  }
  __syncthreads();

  // ---------- output projection + residual ----------
  {
    float acc[4][12];
    #pragma unroll
    for (int j = 0; j < 12; ++j){
      float bj = ws[WS_BQ + 3*CC + o0 + j];
      acc[0][j]=bj; acc[1][j]=bj; acc[2][j]=bj; acc[3][j]=bj;
    }
    const float* WT = ws + WS_WO;
    #pragma unroll 4
    for (int c = 0; c < CC; ++c){
      uint2 ovv = *(const uint2*)&oT[c*72 + tok0];
      float xx[4] = {blo(ovv.x), bhi(ovv.x), blo(ovv.y), bhi(ovv.y)};
      float4 w0 = *(const float4*)&WT[c*CC + o0];
      float4 w1 = *(const float4*)&WT[c*CC + o0 + 4];
      float4 w2 = *(const float4*)&WT[c*CC + o0 + 8];
      float ww[12] = {w0.x,w0.y,w0.z,w0.w,w1.x,w1.y,w1.z,w1.w,w2.x,w2.y,w2.z,w2.w};
      #pragma unroll
      for (int ii = 0; ii < 4; ++ii)
        #pragma unroll
        for (int j = 0; j < 12; ++j)
          acc[ii][j] = fmaf(xx[ii], ww[j], acc[ii][j]);
    }
    int dy = tok0 >> 3, dx0 = tok0 & 7;
    #pragma unroll
    for (int j = 0; j < 12; ++j){
      size_t g = ((size_t)(b*CC + o0 + j)*256 + (y0 + dy))*256 + x0 + dx0;
      float4 r = *(const float4*)&q2d[g];
      float4 o4;
      o4.x = acc[0][j] + r.x;
      o4.y = acc[1][j] + r.y;
      o4.z = acc[2][j] + r.z;
      o4.w = acc[3][j] + r.w;
      *(float4*)&out[g] = o4;
    }
  }
}

extern "C" void kernel_launch(void* const* d_in, const int* in_sizes, int n_in,
                              void* d_out, int out_size, void* d_ws, size_t ws_size,
                              hipStream_t stream)
{
  const float* q2d    = (const float*)d_in[0];
  const float* kv2d   = (const float*)d_in[1];
  const float* wq     = (const float*)d_in[2];
  const float* bq     = (const float*)d_in[3];
  const float* wk     = (const float*)d_in[4];
  const float* bk     = (const float*)d_in[5];
  const float* wv     = (const float*)d_in[6];
  const float* bv     = (const float*)d_in[7];
  const float* in_w   = (const float*)d_in[8];
  const float* in_b   = (const float*)d_in[9];
  const float* out_w  = (const float*)d_in[10];
  const float* out_b  = (const float*)d_in[11];
  const float* proj_w = (const float*)d_in[12];
  const float* proj_b = (const float*)d_in[13];
  float* ws  = (float*)d_ws;
  float* out = (float*)d_out;

  fuse_weights<<<4*CC, CC, 0, stream>>>(wq,bq,wk,bk,wv,bv,in_w,in_b,
                                        out_w,out_b,proj_w,proj_b,ws);
  win_attn<<<NBLK, 256, 0, stream>>>(q2d, kv2d, ws, out);
}